// Round 2
// baseline (258.715 us; speedup 1.0000x reference)
//
#include <hip/hip_runtime.h>
#include <hip/hip_bf16.h>
#include <cstdint>

#define N_NODES 100000
#define HIDDEN  128
#define NEDGE   524288   // E (pos edges; neg same count); 4096 blocks x 128

typedef __attribute__((ext_vector_type(8))) short short8;
typedef __attribute__((ext_vector_type(4))) float f32x4;

__device__ __forceinline__ unsigned short f2b(float f) {
    unsigned u = __float_as_uint(f);
    u += 0x7FFFu + ((u >> 16) & 1u);   // RNE; inputs are finite
    return (unsigned short)(u >> 16);
}
__device__ __forceinline__ float b2f(unsigned x16) {
    return __uint_as_float(x16 << 16);
}

// Wt[table][n][k] = bf16(W1[table*128 + k][n]) — one-time 128KB->64KB transpose.
// Block = one output row (256 blocks of 128 threads). Writes coalesced 256B.
__global__ void wt_kernel(const float* __restrict__ W1,
                          unsigned short* __restrict__ Wt)
{
    const int row = blockIdx.x;          // table*128 + n
    const int n = row & 127;
    const int tb = row >> 7;
    const int k = threadIdx.x;
    Wt[(size_t)row * 128 + k] = f2b(W1[(size_t)(tb * 128 + k) * 128 + n]);
}

// A[m][n] = sum_k z[m][k] * W1half[k][n], stored bf16. No LDS, no barriers:
// one wave per 16 rows. Operands swapped vs canonical so D rows = hidden cols
// -> packed ushort4 stores.
//   Aop[i=t][k=k0+q*8+j] = Wt[n*16+t][k...]      (16B global load, L1/L2-hot)
//   Bop[k=k0+q*8+j][j=t] = bf16(z[m0+t][k...])   (2x float4 + convert)
//   D[i=q*4+r][j=t] = A[m0+t][n*16 + q*4 + r]
__global__ __launch_bounds__(256, 4)
void precompute_kernel(const float* __restrict__ z_src,
                       const float* __restrict__ z_dst,
                       const unsigned short* __restrict__ Wt,
                       unsigned short* __restrict__ Asrc,
                       unsigned short* __restrict__ Adst)
{
    const int table = blockIdx.y;
    const float* z = table ? z_dst : z_src;
    const unsigned short* W = Wt + table * (128 * 128);
    unsigned short* A = table ? Adst : Asrc;

    const int wave = threadIdx.x >> 6;
    const int lane = threadIdx.x & 63;
    const int t = lane & 15;   // node-within-tile (B cols / D cols)
    const int q = lane >> 4;   // K-chunk / D row-quad

    const int m0 = (blockIdx.x * 4 + wave) * 16;
    if (m0 >= N_NODES) return;           // 6250 waves needed; 6252 launched

    const float* zrow = z + (size_t)(m0 + t) * 128;

    f32x4 acc[8];
#pragma unroll
    for (int n = 0; n < 8; ++n) acc[n] = (f32x4){0.f, 0.f, 0.f, 0.f};

#pragma unroll
    for (int ks = 0; ks < 4; ++ks) {
        const int k0 = ks * 32 + q * 8;
        const float4 v0 = *(const float4*)(zrow + k0);
        const float4 v1 = *(const float4*)(zrow + k0 + 4);
        short8 b;
        b[0] = (short)f2b(v0.x); b[1] = (short)f2b(v0.y);
        b[2] = (short)f2b(v0.z); b[3] = (short)f2b(v0.w);
        b[4] = (short)f2b(v1.x); b[5] = (short)f2b(v1.y);
        b[6] = (short)f2b(v1.z); b[7] = (short)f2b(v1.w);
#pragma unroll
        for (int n = 0; n < 8; ++n) {
            const short8 a = *(const short8*)(W + (size_t)(n * 16 + t) * 128 + k0);
            acc[n] = __builtin_amdgcn_mfma_f32_16x16x32_bf16(a, b, acc[n], 0, 0, 0);
        }
    }

    unsigned short* arow = A + (size_t)(m0 + t) * 128;
#pragma unroll
    for (int n = 0; n < 8; ++n) {
        ushort4 h;
        h.x = f2b(acc[n][0]); h.y = f2b(acc[n][1]);
        h.z = f2b(acc[n][2]); h.w = f2b(acc[n][3]);
        *(ushort4*)(arow + n * 16 + q * 4) = h;
    }
}

// 16 lanes per edge; lane owns 8 hidden units (16B bf16 gather per table).
// out[e] = sum_j relu(Asrc[s][j] + Adst[d][j] + b1[j]) * W2[j] + b2
// Block covers 128 edges, entirely pos or entirely neg (NEDGE = 4096*128).
// All 16 gathers issued before any compute for memory-level parallelism.
__global__ __launch_bounds__(256, 4)
void edge_kernel(const unsigned short* __restrict__ Asrc,
                 const unsigned short* __restrict__ Adst,
                 const int* __restrict__ pos_src,
                 const int* __restrict__ pos_dst,
                 const int* __restrict__ neg_src,
                 const int* __restrict__ neg_dst,
                 const float* __restrict__ b1,
                 const float* __restrict__ W2,
                 const float* __restrict__ b2,
                 float* __restrict__ out)
{
    const int tid = threadIdx.x;
    const int t = tid & 15;      // hidden slice t*8 .. t*8+7
    const int g = tid >> 4;      // edge group within block (0..15)

    const bool is_pos = blockIdx.x < 4096;
    const int* __restrict__ sp = is_pos ? pos_src : neg_src;
    const int* __restrict__ dp = is_pos ? pos_dst : neg_dst;
    const int eb = (is_pos ? blockIdx.x : blockIdx.x - 4096) * 128;

    float b1r[8], w2r[8];
#pragma unroll
    for (int j = 0; j < 8; ++j) {
        b1r[j] = b1[t * 8 + j];
        w2r[j] = W2[t * 8 + j];
    }
    const float bias2 = b2[0];

    int sidx[8], didx[8];
#pragma unroll
    for (int i = 0; i < 8; ++i) {
        sidx[i] = sp[eb + i * 16 + g];
        didx[i] = dp[eb + i * 16 + g];
    }

    uint4 ua[8], ub[8];
#pragma unroll
    for (int i = 0; i < 8; ++i) {
        ua[i] = *(const uint4*)(Asrc + (size_t)sidx[i] * 128 + t * 8);
        ub[i] = *(const uint4*)(Adst + (size_t)didx[i] * 128 + t * 8);
    }

#pragma unroll
    for (int i = 0; i < 8; ++i) {
        float acc = 0.f;
        const unsigned* pa = (const unsigned*)&ua[i];
        const unsigned* pb = (const unsigned*)&ub[i];
#pragma unroll
        for (int j2 = 0; j2 < 4; ++j2) {
            float h0 = b2f(pa[j2] & 0xFFFFu) + b2f(pb[j2] & 0xFFFFu) + b1r[2 * j2];
            float h1 = b2f(pa[j2] >> 16)     + b2f(pb[j2] >> 16)     + b1r[2 * j2 + 1];
            h0 = fmaxf(h0, 0.f);
            h1 = fmaxf(h1, 0.f);
            acc = fmaf(h0, w2r[2 * j2], acc);
            acc = fmaf(h1, w2r[2 * j2 + 1], acc);
        }
        acc += __shfl_xor(acc, 1);
        acc += __shfl_xor(acc, 2);
        acc += __shfl_xor(acc, 4);
        acc += __shfl_xor(acc, 8);
        if (t == 0) out[blockIdx.x * 128 + i * 16 + g] = acc + bias2;
    }
}

extern "C" void kernel_launch(void* const* d_in, const int* in_sizes, int n_in,
                              void* d_out, int out_size, void* d_ws, size_t ws_size,
                              hipStream_t stream) {
    const float* z_src  = (const float*)d_in[0];
    const float* z_dst  = (const float*)d_in[1];
    const int* pos_src  = (const int*)d_in[2];
    const int* pos_dst  = (const int*)d_in[3];
    const int* neg_src  = (const int*)d_in[4];
    const int* neg_dst  = (const int*)d_in[5];
    const float* W1     = (const float*)d_in[6];
    const float* b1     = (const float*)d_in[7];
    const float* W2     = (const float*)d_in[8];
    const float* b2     = (const float*)d_in[9];
    float* out = (float*)d_out;

    unsigned short* Asrc = (unsigned short*)d_ws;                 // 25.6 MB
    unsigned short* Adst = Asrc + (size_t)N_NODES * HIDDEN;       // 25.6 MB
    unsigned short* Wt   = Adst + (size_t)N_NODES * HIDDEN;       // 64 KB

    wt_kernel<<<256, 128, 0, stream>>>(W1, Wt);

    dim3 pgrid(1563, 2);   // ceil(6250 wave-tiles / 4 per block), 2 tables
    precompute_kernel<<<pgrid, 256, 0, stream>>>(z_src, z_dst, Wt, Asrc, Adst);

    edge_kernel<<<8192, 256, 0, stream>>>(Asrc, Adst, pos_src, pos_dst,
                                          neg_src, neg_dst, b1, W2, b2, out);
}